// Round 1
// baseline (2593.957 us; speedup 1.0000x reference)
//
#include <hip/hip_runtime.h>
#include <math.h>

#define D_MODEL 768
#define NH      12
#define DK      64
#define SEQ     1024
#define NB      8
#define MTOT    (NB*SEQ)     // 8192
#define SCALE   0.125f       // 1/sqrt(64)

// ---------------------------------------------------------------------------
// GEMM: C = A @ W^T + bias.  A:[M,768] row-major, W:[N=768,K=768] row-major.
// OUT_MODE 0: C[m][n] -> C[m*768 + n]
// OUT_MODE 1: write [B,H,S,DK] layout: ((b*NH+h)*SEQ+s)*DK + d
// ---------------------------------------------------------------------------
#define BMg 128
#define BNg 128
#define BKg 16

template<int OUT_MODE>
__global__ __launch_bounds__(256) void gemm_at_wt(
    const float* __restrict__ A, const float* __restrict__ W,
    const float* __restrict__ bias, float* __restrict__ C)
{
    __shared__ float As[BKg][BMg + 4];
    __shared__ float Ws[BKg][BNg + 4];
    const int tid = threadIdx.x;
    const int tx = tid & 15, ty = tid >> 4;
    const int n0 = blockIdx.x * BNg, m0 = blockIdx.y * BMg;
    const int lrow = tid >> 1, lc8 = (tid & 1) * 8;

    float acc[8][8];
    #pragma unroll
    for (int i = 0; i < 8; ++i)
        #pragma unroll
        for (int j = 0; j < 8; ++j) acc[i][j] = 0.f;

    const float* Ap = A + (size_t)(m0 + lrow) * D_MODEL + lc8;
    const float* Wp = W + (size_t)(n0 + lrow) * D_MODEL + lc8;

    for (int k0 = 0; k0 < D_MODEL; k0 += BKg) {
        float4 a0 = *(const float4*)(Ap + k0);
        float4 a1 = *(const float4*)(Ap + k0 + 4);
        float4 w0 = *(const float4*)(Wp + k0);
        float4 w1 = *(const float4*)(Wp + k0 + 4);
        __syncthreads();   // previous tile fully consumed before overwrite
        As[lc8+0][lrow] = a0.x; As[lc8+1][lrow] = a0.y;
        As[lc8+2][lrow] = a0.z; As[lc8+3][lrow] = a0.w;
        As[lc8+4][lrow] = a1.x; As[lc8+5][lrow] = a1.y;
        As[lc8+6][lrow] = a1.z; As[lc8+7][lrow] = a1.w;
        Ws[lc8+0][lrow] = w0.x; Ws[lc8+1][lrow] = w0.y;
        Ws[lc8+2][lrow] = w0.z; Ws[lc8+3][lrow] = w0.w;
        Ws[lc8+4][lrow] = w1.x; Ws[lc8+5][lrow] = w1.y;
        Ws[lc8+6][lrow] = w1.z; Ws[lc8+7][lrow] = w1.w;
        __syncthreads();
        #pragma unroll
        for (int kk = 0; kk < BKg; ++kk) {
            float am[8], wn[8];
            *(float4*)&am[0] = *(const float4*)&As[kk][ty*8];
            *(float4*)&am[4] = *(const float4*)&As[kk][ty*8+4];
            *(float4*)&wn[0] = *(const float4*)&Ws[kk][tx*8];
            *(float4*)&wn[4] = *(const float4*)&Ws[kk][tx*8+4];
            #pragma unroll
            for (int i = 0; i < 8; ++i)
                #pragma unroll
                for (int j = 0; j < 8; ++j)
                    acc[i][j] = fmaf(am[i], wn[j], acc[i][j]);
        }
    }

    float bv[8];
    #pragma unroll
    for (int j = 0; j < 8; ++j) bv[j] = bias[n0 + tx*8 + j];

    if (OUT_MODE == 0) {
        #pragma unroll
        for (int i = 0; i < 8; ++i) {
            int m = m0 + ty*8 + i;
            float4 o0, o1;
            o0.x = acc[i][0]+bv[0]; o0.y = acc[i][1]+bv[1];
            o0.z = acc[i][2]+bv[2]; o0.w = acc[i][3]+bv[3];
            o1.x = acc[i][4]+bv[4]; o1.y = acc[i][5]+bv[5];
            o1.z = acc[i][6]+bv[6]; o1.w = acc[i][7]+bv[7];
            *(float4*)&C[(size_t)m*D_MODEL + n0 + tx*8]     = o0;
            *(float4*)&C[(size_t)m*D_MODEL + n0 + tx*8 + 4] = o1;
        }
    } else {
        const int nb = n0 + tx*8;
        const int h = nb >> 6, d0 = nb & 63;   // 8-col group never straddles a head
        #pragma unroll
        for (int i = 0; i < 8; ++i) {
            int m = m0 + ty*8 + i;
            int b = m >> 10, s = m & (SEQ-1);
            size_t idx = (((size_t)b*NH + h)*SEQ + s)*DK + d0;
            float4 o0, o1;
            o0.x = acc[i][0]+bv[0]; o0.y = acc[i][1]+bv[1];
            o0.z = acc[i][2]+bv[2]; o0.w = acc[i][3]+bv[3];
            o1.x = acc[i][4]+bv[4]; o1.y = acc[i][5]+bv[5];
            o1.z = acc[i][6]+bv[6]; o1.w = acc[i][7]+bv[7];
            *(float4*)&C[idx]     = o0;
            *(float4*)&C[idx + 4] = o1;
        }
    }
}

// ---------------------------------------------------------------------------
// Fused attention with 3x3 depthwise conv suppression on the score image.
// One block = (b, h, 8 query rows). Computes 10 score rows (with +-1 halo)
// over all 1024 keys in LDS, then conv -> softmax -> PV.
// ---------------------------------------------------------------------------
#define TQ 8

__device__ __forceinline__ float blk_reduce_max(float v, float* red, int tid) {
    __syncthreads();   // also orders conv reads before prob overwrite
    #pragma unroll
    for (int off = 32; off >= 1; off >>= 1)
        v = fmaxf(v, __shfl_xor(v, off));
    if ((tid & 63) == 0) red[tid >> 6] = v;
    __syncthreads();
    return fmaxf(fmaxf(red[0], red[1]), fmaxf(red[2], red[3]));
}

__device__ __forceinline__ float blk_reduce_sum(float v, float* red, int tid) {
    __syncthreads();
    #pragma unroll
    for (int off = 32; off >= 1; off >>= 1)
        v += __shfl_xor(v, off);
    if ((tid & 63) == 0) red[tid >> 6] = v;
    __syncthreads();
    return red[0] + red[1] + red[2] + red[3];
}

__global__ __launch_bounds__(256) void attn_kernel(
    const float* __restrict__ Q, const float* __restrict__ K,
    const float* __restrict__ V, const float* __restrict__ CW,
    float* __restrict__ Ao)
{
    __shared__ float Ssc[TQ+2][SEQ];     // 40 KB: raw scores, then probs
    __shared__ float Qs[TQ+2][DK];       // 2.5 KB (scale folded in)
    __shared__ float wcv[9];
    __shared__ float red[4];
    __shared__ float rowsum[TQ];
    __shared__ float part[4][TQ][DK];    // 8 KB PV partials

    const int tid = threadIdx.x;
    const int q0 = blockIdx.x * TQ;
    const int bh = blockIdx.y;
    const int h = bh % NH, b = bh / NH;
    const float* Qb = Q + (size_t)bh * SEQ * DK;
    const float* Kb = K + (size_t)bh * SEQ * DK;
    const float* Vb = V + (size_t)bh * SEQ * DK;

    if (tid < 9) wcv[tid] = CW[h*9 + tid];
    for (int i = tid; i < (TQ+2)*DK; i += 256) {
        int r = i >> 6, d = i & 63;
        int qr = q0 - 1 + r;
        Qs[r][d] = (qr >= 0 && qr < SEQ) ? Qb[(size_t)qr*DK + d] * SCALE : 0.f;
    }
    __syncthreads();

    // ---- QK^T: each thread owns 4 key columns, computes all 10 rows ----
    for (int c = 0; c < 4; ++c) {
        const int k = c*256 + tid;
        const float4* Kr = (const float4*)(Kb + (size_t)k * DK);
        float acc[TQ+2];
        #pragma unroll
        for (int r = 0; r < TQ+2; ++r) acc[r] = 0.f;
        #pragma unroll
        for (int j = 0; j < DK/4; ++j) {
            float4 kv = Kr[j];
            #pragma unroll
            for (int r = 0; r < TQ+2; ++r) {
                float4 qv = *(const float4*)&Qs[r][j*4];
                acc[r] = fmaf(kv.x, qv.x, acc[r]);
                acc[r] = fmaf(kv.y, qv.y, acc[r]);
                acc[r] = fmaf(kv.z, qv.z, acc[r]);
                acc[r] = fmaf(kv.w, qv.w, acc[r]);
            }
        }
        #pragma unroll
        for (int r = 0; r < TQ+2; ++r) Ssc[r][k] = acc[r];
    }
    __syncthreads();

    // ---- conv + softmax per row; probs for row r go to dead slot r-1 ----
    for (int r = 1; r <= TQ; ++r) {
        float tloc[4];
        float tmax = -1e30f;
        #pragma unroll
        for (int c = 0; c < 4; ++c) {
            const int k = c*256 + tid;
            float supp = 0.f;
            #pragma unroll
            for (int a = 0; a < 3; ++a) {
                const float* Sr = Ssc[r-1+a];
                float s0 = (k > 0)     ? Sr[k-1] : 0.f;
                float s1 = Sr[k];
                float s2 = (k < SEQ-1) ? Sr[k+1] : 0.f;
                supp = fmaf(wcv[a*3+0], s0, supp);
                supp = fmaf(wcv[a*3+1], s1, supp);
                supp = fmaf(wcv[a*3+2], s2, supp);
            }
            float t = Ssc[r][k] - supp;
            tloc[c] = t;
            tmax = fmaxf(tmax, t);
        }
        float bmax = blk_reduce_max(tmax, red, tid);  // sync inside
        float lsum = 0.f;
        #pragma unroll
        for (int c = 0; c < 4; ++c) {
            const int k = c*256 + tid;
            float p = __expf(tloc[c] - bmax);
            lsum += p;
            Ssc[r-1][k] = p;
        }
        float bsum = blk_reduce_sum(lsum, red, tid);  // sync inside
        if (tid == 0) rowsum[r-1] = bsum;
    }
    __syncthreads();

    // ---- PV: wave cw handles key chunk [cw*256, cw*256+256), lane = dim ----
    {
        const int d = tid & 63, cw = tid >> 6;
        float acc[TQ];
        #pragma unroll
        for (int q = 0; q < TQ; ++q) acc[q] = 0.f;
        for (int kk = cw*256; kk < cw*256 + 256; ++kk) {
            float vkd = Vb[(size_t)kk*DK + d];
            #pragma unroll
            for (int q = 0; q < TQ; ++q)
                acc[q] = fmaf(Ssc[q][kk], vkd, acc[q]);
        }
        #pragma unroll
        for (int q = 0; q < TQ; ++q) part[cw][q][d] = acc[q];
    }
    __syncthreads();

    for (int i = tid; i < TQ*DK; i += 256) {
        int qq = i >> 6, dd = i & 63;
        float val = part[0][qq][dd] + part[1][qq][dd]
                  + part[2][qq][dd] + part[3][qq][dd];
        val = val / rowsum[qq];
        Ao[((size_t)b*SEQ + (q0 + qq))*D_MODEL + h*DK + dd] = val;
    }
}

// ---------------------------------------------------------------------------
extern "C" void kernel_launch(void* const* d_in, const int* in_sizes, int n_in,
                              void* d_out, int out_size, void* d_ws, size_t ws_size,
                              hipStream_t stream)
{
    const float* q  = (const float*)d_in[0];
    const float* k  = (const float*)d_in[1];
    const float* v  = (const float*)d_in[2];
    const float* wq = (const float*)d_in[3];
    const float* bq = (const float*)d_in[4];
    const float* wk = (const float*)d_in[5];
    const float* bk = (const float*)d_in[6];
    const float* wv = (const float*)d_in[7];
    const float* bv = (const float*)d_in[8];
    const float* wo = (const float*)d_in[9];
    const float* bo = (const float*)d_in[10];
    const float* cw = (const float*)d_in[11];
    float* out = (float*)d_out;

    const size_t NELT = (size_t)MTOT * D_MODEL;  // 6,291,456 floats each
    float* Qp  = (float*)d_ws;       // [B,H,S,DK]
    float* Kp  = Qp + NELT;
    float* Vp  = Kp + NELT;
    float* Aop = Vp + NELT;          // [B,S,D_MODEL]

    dim3 gg(D_MODEL / BNg, MTOT / BMg);   // (6, 64)
    gemm_at_wt<1><<<gg, 256, 0, stream>>>(q, wq, bq, Qp);
    gemm_at_wt<1><<<gg, 256, 0, stream>>>(k, wk, bk, Kp);
    gemm_at_wt<1><<<gg, 256, 0, stream>>>(v, wv, bv, Vp);
    attn_kernel<<<dim3(SEQ/TQ, NB*NH), 256, 0, stream>>>(Qp, Kp, Vp, cw, Aop);
    gemm_at_wt<0><<<gg, 256, 0, stream>>>(Aop, wo, bo, out);
}

// Round 2
// 317.703 us; speedup vs baseline: 8.1647x; 8.1647x over previous
//
#include <hip/hip_runtime.h>
#include <math.h>

typedef __attribute__((ext_vector_type(8))) short short8;
typedef __attribute__((ext_vector_type(4))) float f32x4;
typedef __attribute__((ext_vector_type(4))) unsigned short ushort4v;

#define D_MODEL 768
#define NH      12
#define DK      64
#define SEQ     1024
#define NB      8
#define MTOT    (NB*SEQ)                  // 8192
#define NELT    ((size_t)MTOT*D_MODEL)    // 6291456
#define WELT    ((size_t)D_MODEL*D_MODEL) // 589824

__device__ __forceinline__ unsigned short f2bf(float f) {
    unsigned int u = __builtin_bit_cast(unsigned int, f);
    unsigned int r = (u + 0x7FFFu + ((u >> 16) & 1u)) >> 16;   // RNE
    return (unsigned short)r;
}
__device__ __forceinline__ float bf2f(unsigned short h) {
    return __builtin_bit_cast(float, ((unsigned int)h) << 16);
}
__device__ __forceinline__ void gload_lds16(const void* g, void* lds) {
    __builtin_amdgcn_global_load_lds(
        (const __attribute__((address_space(1))) unsigned int*)g,
        (__attribute__((address_space(3))) unsigned int*)lds, 16, 0, 0);
}

// ---------------------------------------------------------------------------
// fp32 -> bf16 converts
// ---------------------------------------------------------------------------
__global__ __launch_bounds__(256) void cvt3(
    const float* __restrict__ a, const float* __restrict__ b, const float* __restrict__ c,
    unsigned short* __restrict__ oa, unsigned short* __restrict__ ob, unsigned short* __restrict__ oc)
{
    size_t i = (size_t)blockIdx.x * 256 + threadIdx.x;   // 8 elems per thread
    const size_t per = NELT / 8;
    const float* s; unsigned short* d; size_t l;
    if (i < per)            { s = a; d = oa; l = i; }
    else if (i < 2*per)     { s = b; d = ob; l = i - per; }
    else                    { s = c; d = oc; l = i - 2*per; }
    const float4* sp = (const float4*)(s + l*8);
    float4 v0 = sp[0], v1 = sp[1];
    short8 o;
    o[0]=(short)f2bf(v0.x); o[1]=(short)f2bf(v0.y); o[2]=(short)f2bf(v0.z); o[3]=(short)f2bf(v0.w);
    o[4]=(short)f2bf(v1.x); o[5]=(short)f2bf(v1.y); o[6]=(short)f2bf(v1.z); o[7]=(short)f2bf(v1.w);
    *(short8*)(d + l*8) = o;
}

__global__ __launch_bounds__(256) void cvt4(
    const float* __restrict__ a, const float* __restrict__ b,
    const float* __restrict__ c, const float* __restrict__ e,
    unsigned short* __restrict__ oa, unsigned short* __restrict__ ob,
    unsigned short* __restrict__ oc, unsigned short* __restrict__ oe)
{
    size_t i = (size_t)blockIdx.x * 256 + threadIdx.x;
    const size_t per = WELT / 8;
    const float* s; unsigned short* d; size_t l;
    if (i < per)        { s = a; d = oa; l = i; }
    else if (i < 2*per) { s = b; d = ob; l = i - per; }
    else if (i < 3*per) { s = c; d = oc; l = i - 2*per; }
    else                { s = e; d = oe; l = i - 3*per; }
    const float4* sp = (const float4*)(s + l*8);
    float4 v0 = sp[0], v1 = sp[1];
    short8 o;
    o[0]=(short)f2bf(v0.x); o[1]=(short)f2bf(v0.y); o[2]=(short)f2bf(v0.z); o[3]=(short)f2bf(v0.w);
    o[4]=(short)f2bf(v1.x); o[5]=(short)f2bf(v1.y); o[6]=(short)f2bf(v1.z); o[7]=(short)f2bf(v1.w);
    *(short8*)(d + l*8) = o;
}

// ---------------------------------------------------------------------------
// bf16 MFMA GEMM: C = A @ W^T + bias.  A:[8192][768], W:[768][768] (row-major).
// MODE 0: bf16 row-major [8192][768], value = (acc+bias)*scale
// MODE 1: bf16 V^T layout [B,H,DK,SEQ]
// MODE 2: fp32 row-major [8192][768] + bias
// ---------------------------------------------------------------------------
#define BM 128
#define BN 128
#define BKG 64

template<int MODE>
__global__ __launch_bounds__(256) void gemm_bf16(
    const unsigned short* __restrict__ A, const unsigned short* __restrict__ W,
    const float* __restrict__ bias, void* __restrict__ Cout, float scale)
{
    __shared__ unsigned short As[BM*BKG];   // 16 KB, swizzled
    __shared__ unsigned short Bs[BN*BKG];
    const int tid = threadIdx.x;
    const int lane = tid & 63, wid = tid >> 6;
    const int wr = wid >> 1, wc = wid & 1;
    const int m0 = blockIdx.y * BM, n0 = blockIdx.x * BN;

    f32x4 acc[4][4];
    #pragma unroll
    for (int i = 0; i < 4; ++i)
        #pragma unroll
        for (int j = 0; j < 4; ++j) acc[i][j] = (f32x4)(0.f);

    for (int k0 = 0; k0 < D_MODEL; k0 += BKG) {
        __syncthreads();
        #pragma unroll
        for (int j = 0; j < 4; ++j) {
            int p = ((wid*4 + j) << 9) + lane*8;     // elem pos in 8192-elem tile
            int row = p >> 6, off = p & 63;
            const unsigned short* srcA = A + (size_t)(m0+row)*D_MODEL + k0 + (off ^ ((row&7)<<3));
            gload_lds16(srcA, &As[(wid*4 + j) << 9]);
            const unsigned short* srcB = W + (size_t)(n0+row)*D_MODEL + k0 + (off ^ ((row&7)<<3));
            gload_lds16(srcB, &Bs[(wid*4 + j) << 9]);
        }
        __syncthreads();
        #pragma unroll
        for (int ks = 0; ks < 2; ++ks) {
            short8 af[4], bf8[4];
            #pragma unroll
            for (int mi = 0; mi < 4; ++mi) {
                int row = wr*64 + mi*16 + (lane & 15);
                af[mi] = *(const short8*)&As[row*BKG + ((ks*32 + (lane>>4)*8) ^ ((row&7)<<3))];
            }
            #pragma unroll
            for (int ni = 0; ni < 4; ++ni) {
                int row = wc*64 + ni*16 + (lane & 15);
                bf8[ni] = *(const short8*)&Bs[row*BKG + ((ks*32 + (lane>>4)*8) ^ ((row&7)<<3))];
            }
            #pragma unroll
            for (int mi = 0; mi < 4; ++mi)
                #pragma unroll
                for (int ni = 0; ni < 4; ++ni)
                    acc[mi][ni] = __builtin_amdgcn_mfma_f32_16x16x32_bf16(af[mi], bf8[ni], acc[mi][ni], 0, 0, 0);
        }
    }

    float bv[4];
    #pragma unroll
    for (int ni = 0; ni < 4; ++ni) bv[ni] = bias[n0 + wc*64 + ni*16 + (lane & 15)];

    if (MODE == 0) {
        unsigned short* C = (unsigned short*)Cout;
        #pragma unroll
        for (int mi = 0; mi < 4; ++mi)
            #pragma unroll
            for (int ni = 0; ni < 4; ++ni) {
                int col = n0 + wc*64 + ni*16 + (lane & 15);
                int rbase = m0 + wr*64 + mi*16 + ((lane>>4)<<2);
                #pragma unroll
                for (int j = 0; j < 4; ++j)
                    C[(size_t)(rbase+j)*D_MODEL + col] = f2bf((acc[mi][ni][j] + bv[ni]) * scale);
            }
    } else if (MODE == 1) {
        unsigned short* C = (unsigned short*)Cout;
        #pragma unroll
        for (int mi = 0; mi < 4; ++mi)
            #pragma unroll
            for (int ni = 0; ni < 4; ++ni) {
                int col = n0 + wc*64 + ni*16 + (lane & 15);
                int hh = col >> 6, dd = col & 63;
                int m = m0 + wr*64 + mi*16 + ((lane>>4)<<2);
                int bb = m >> 10, ss = m & (SEQ-1);
                ushort4v pk;
                #pragma unroll
                for (int j = 0; j < 4; ++j) pk[j] = f2bf(acc[mi][ni][j] + bv[ni]);
                *(ushort4v*)&C[((size_t)(bb*NH + hh)*DK + dd)*SEQ + ss] = pk;
            }
    } else {
        float* C = (float*)Cout;
        #pragma unroll
        for (int mi = 0; mi < 4; ++mi)
            #pragma unroll
            for (int ni = 0; ni < 4; ++ni) {
                int col = n0 + wc*64 + ni*16 + (lane & 15);
                int rbase = m0 + wr*64 + mi*16 + ((lane>>4)<<2);
                #pragma unroll
                for (int j = 0; j < 4; ++j)
                    C[(size_t)(rbase+j)*D_MODEL + col] = acc[mi][ni][j] + bv[ni];
            }
    }
}

// ---------------------------------------------------------------------------
// Fused MFMA attention with 3x3 depthwise conv suppression.
// Block = (b,h) x 32 query rows. 8 waves. Computes 48 score rows
// (rows q0-8..q0+39; conv needs q0-1..q0+32) over all 1024 keys in LDS.
// ---------------------------------------------------------------------------
__global__ __launch_bounds__(512) void attn_mfma(
    const unsigned short* __restrict__ Qp,   // [8192][768] bf16 (scale folded)
    const unsigned short* __restrict__ Kp,   // [8192][768] bf16
    const unsigned short* __restrict__ Vt,   // [96][64][1024] bf16
    const float* __restrict__ CW,
    unsigned short* __restrict__ Aop)        // [8192][768] bf16
{
    __shared__ unsigned short Ss[48*1024];   // 96 KB scores->probs, swizzled
    __shared__ unsigned short Qs[48*64];     // 6 KB
    __shared__ unsigned short KVs[64*256];   // 32 KB K-chunk / Vt-chunk

    const int tid = threadIdx.x;
    const int lane = tid & 63, wid = tid >> 6;
    const int q0 = blockIdx.x * 32;
    const int bh = blockIdx.y;
    const int h = bh % NH, b = bh / NH;

    float wcv[9];
    #pragma unroll
    for (int i = 0; i < 9; ++i) wcv[i] = CW[h*9 + i];

    // stage Q rows q0-8 .. q0+39 (zero OOB), swizzled
    if (tid < 384) {
        int row = tid >> 3, slot = tid & 7;
        int g = q0 - 8 + row;
        short8 val = (short8)0;
        if (g >= 0 && g < SEQ)
            val = *(const short8*)&Qp[(size_t)(b*SEQ + g)*D_MODEL + h*DK + slot*8];
        *(short8*)&Qs[row*64 + ((slot ^ (row&7)) << 3)] = val;
    }

    // ---- QK^T over 4 chunks of 256 keys ----
    for (int ck = 0; ck < 4; ++ck) {
        __syncthreads();
        #pragma unroll
        for (int j = 0; j < 4; ++j) {
            int p = ((wid*4 + j) << 9) + lane*8;
            int row = p >> 6, off = p & 63;
            int g = ck*256 + row;
            const unsigned short* src = Kp + (size_t)(b*SEQ + g)*D_MODEL + h*DK + (off ^ ((row&7)<<3));
            gload_lds16(src, &KVs[(wid*4 + j) << 9]);
        }
        __syncthreads();

        f32x4 sacc[3][2];
        #pragma unroll
        for (int mi = 0; mi < 3; ++mi)
            #pragma unroll
            for (int ni = 0; ni < 2; ++ni) sacc[mi][ni] = (f32x4)(0.f);
        #pragma unroll
        for (int ks = 0; ks < 2; ++ks) {
            short8 af[3], bf8[2];
            #pragma unroll
            for (int mi = 0; mi < 3; ++mi) {
                int row = mi*16 + (lane & 15);
                af[mi] = *(const short8*)&Qs[row*64 + ((ks*32 + (lane>>4)*8) ^ ((row&7)<<3))];
            }
            #pragma unroll
            for (int ni = 0; ni < 2; ++ni) {
                int row = wid*32 + ni*16 + (lane & 15);
                bf8[ni] = *(const short8*)&KVs[row*64 + ((ks*32 + (lane>>4)*8) ^ ((row&7)<<3))];
            }
            #pragma unroll
            for (int mi = 0; mi < 3; ++mi)
                #pragma unroll
                for (int ni = 0; ni < 2; ++ni)
                    sacc[mi][ni] = __builtin_amdgcn_mfma_f32_16x16x32_bf16(af[mi], bf8[ni], sacc[mi][ni], 0, 0, 0);
        }
        #pragma unroll
        for (int mi = 0; mi < 3; ++mi)
            #pragma unroll
            for (int ni = 0; ni < 2; ++ni) {
                int col = ck*256 + wid*32 + ni*16 + (lane & 15);
                #pragma unroll
                for (int j = 0; j < 4; ++j) {
                    int row = mi*16 + ((lane>>4)<<2) + j;
                    Ss[row*1024 + (col ^ ((row&7)<<3))] = f2bf(sacc[mi][ni][j]);
                }
            }
    }
    __syncthreads();   // all scores in Ss

    // ---- conv + softmax: wave wid owns LDS rows 8+4w .. 11+4w; 16 cols/lane ----
    short8 prow[4][2];
    const int c0 = lane * 16;
    #pragma unroll
    for (int rr = 0; rr < 4; ++rr) {
        int r = 8 + wid*4 + rr;
        float sm1[16], s0[16], sp1[16];
        {
            int rows[3] = {r-1, r, r+1};
            float* outs[3] = {sm1, s0, sp1};
            #pragma unroll
            for (int a = 0; a < 3; ++a) {
                int row = rows[a];
                short8 v0 = *(const short8*)&Ss[row*1024 + ( c0      ^ ((row&7)<<3))];
                short8 v1 = *(const short8*)&Ss[row*1024 + ((c0 + 8) ^ ((row&7)<<3))];
                #pragma unroll
                for (int i = 0; i < 8; ++i) {
                    outs[a][i]   = bf2f((unsigned short)v0[i]);
                    outs[a][8+i] = bf2f((unsigned short)v1[i]);
                }
            }
        }
        float lA = __shfl_up(sm1[15], 1), lB = __shfl_up(s0[15], 1), lC = __shfl_up(sp1[15], 1);
        float rA = __shfl_down(sm1[0], 1), rB = __shfl_down(s0[0], 1), rC = __shfl_down(sp1[0], 1);
        if (lane == 0)  { lA = 0.f; lB = 0.f; lC = 0.f; }
        if (lane == 63) { rA = 0.f; rB = 0.f; rC = 0.f; }

        float t[16], tmax = -1e30f;
        #pragma unroll
        for (int i = 0; i < 16; ++i) {
            float a0 = (i > 0)  ? sm1[i-1] : lA;
            float a2 = (i < 15) ? sm1[i+1] : rA;
            float b0 = (i > 0)  ? s0[i-1]  : lB;
            float b2 = (i < 15) ? s0[i+1]  : rB;
            float g0 = (i > 0)  ? sp1[i-1] : lC;
            float g2 = (i < 15) ? sp1[i+1] : rC;
            float supp = wcv[0]*a0 + wcv[1]*sm1[i] + wcv[2]*a2
                       + wcv[3]*b0 + wcv[4]*s0[i]  + wcv[5]*b2
                       + wcv[6]*g0 + wcv[7]*sp1[i] + wcv[8]*g2;
            t[i] = s0[i] - supp;
            tmax = fmaxf(tmax, t[i]);
        }
        #pragma unroll
        for (int o = 1; o < 64; o <<= 1) tmax = fmaxf(tmax, __shfl_xor(tmax, o));
        float p[16], lsum = 0.f;
        #pragma unroll
        for (int i = 0; i < 16; ++i) { p[i] = __expf(t[i] - tmax); lsum += p[i]; }
        #pragma unroll
        for (int o = 1; o < 64; o <<= 1) lsum += __shfl_xor(lsum, o);
        float inv = 1.0f / lsum;
        #pragma unroll
        for (int i = 0; i < 8; ++i) prow[rr][0][i] = (short)f2bf(p[i] * inv);
        #pragma unroll
        for (int i = 0; i < 8; ++i) prow[rr][1][i] = (short)f2bf(p[8+i] * inv);
    }
    __syncthreads();   // all conv reads complete
    #pragma unroll
    for (int rr = 0; rr < 4; ++rr) {
        int row = 8 + wid*4 + rr;
        *(short8*)&Ss[row*1024 + ( c0      ^ ((row&7)<<3))] = prow[rr][0];
        *(short8*)&Ss[row*1024 + ((c0 + 8) ^ ((row&7)<<3))] = prow[rr][1];
    }
    __syncthreads();

    // ---- PV: O[32x64] = P[32x1024] @ V[1024x64], V^T chunks in LDS ----
    const int mw = wid >> 2, nw = wid & 3;
    f32x4 oacc = (f32x4)(0.f);
    for (int ck = 0; ck < 4; ++ck) {
        if (ck) __syncthreads();
        #pragma unroll
        for (int j = 0; j < 4; ++j) {
            int p = ((wid*4 + j) << 9) + lane*8;
            int row = p >> 8, off = p & 255;     // row = d, off = s within chunk
            const unsigned short* src = Vt + ((size_t)(bh*DK + row))*SEQ + ck*256 + (off ^ ((row&7)<<3));
            gload_lds16(src, &KVs[(wid*4 + j) << 9]);
        }
        __syncthreads();
        #pragma unroll
        for (int ks = 0; ks < 8; ++ks) {
            int pr_ = 8 + mw*16 + (lane & 15);
            short8 pa = *(const short8*)&Ss[pr_*1024 + ((ck*256 + ks*32 + (lane>>4)*8) ^ ((pr_&7)<<3))];
            int vr = nw*16 + (lane & 15);
            short8 vb8 = *(const short8*)&KVs[vr*256 + ((ks*32 + (lane>>4)*8) ^ ((vr&7)<<3))];
            oacc = __builtin_amdgcn_mfma_f32_16x16x32_bf16(pa, vb8, oacc, 0, 0, 0);
        }
    }
    {
        int col = h*DK + nw*16 + (lane & 15);
        int mbase = q0 + mw*16 + ((lane>>4)<<2);
        #pragma unroll
        for (int j = 0; j < 4; ++j)
            Aop[(size_t)(b*SEQ + mbase + j)*D_MODEL + col] = f2bf(oacc[j]);
    }
}

// ---------------------------------------------------------------------------
extern "C" void kernel_launch(void* const* d_in, const int* in_sizes, int n_in,
                              void* d_out, int out_size, void* d_ws, size_t ws_size,
                              hipStream_t stream)
{
    const float* q  = (const float*)d_in[0];
    const float* k  = (const float*)d_in[1];
    const float* v  = (const float*)d_in[2];
    const float* wq = (const float*)d_in[3];
    const float* bq = (const float*)d_in[4];
    const float* wk = (const float*)d_in[5];
    const float* bk = (const float*)d_in[6];
    const float* wv = (const float*)d_in[7];
    const float* bv = (const float*)d_in[8];
    const float* wo = (const float*)d_in[9];
    const float* bo = (const float*)d_in[10];
    const float* cw = (const float*)d_in[11];

    unsigned short* qb  = (unsigned short*)d_ws;
    unsigned short* kb  = qb  + NELT;
    unsigned short* vb  = kb  + NELT;
    unsigned short* wqb = vb  + NELT;
    unsigned short* wkb = wqb + WELT;
    unsigned short* wvb = wkb + WELT;
    unsigned short* wob = wvb + WELT;
    unsigned short* Qp  = wob + WELT;
    unsigned short* Kp  = Qp  + NELT;
    unsigned short* Vtp = Kp  + NELT;
    unsigned short* Aop = Vtp + NELT;

    cvt3<<<(int)(3*NELT/8/256), 256, 0, stream>>>(q, k, v, qb, kb, vb);
    cvt4<<<(int)(4*WELT/8/256), 256, 0, stream>>>(wq, wk, wv, wo, wqb, wkb, wvb, wob);

    dim3 gg(D_MODEL/BN, MTOT/BM);   // (6, 64)
    gemm_bf16<0><<<gg, 256, 0, stream>>>(qb, wqb, bq, Qp, 0.125f);
    gemm_bf16<0><<<gg, 256, 0, stream>>>(kb, wkb, bk, Kp, 1.0f);
    gemm_bf16<1><<<gg, 256, 0, stream>>>(vb, wvb, bv, Vtp, 1.0f);

    attn_mfma<<<dim3(SEQ/32, NB*NH), 512, 0, stream>>>(Qp, Kp, Vtp, cw, Aop);

    gemm_bf16<2><<<gg, 256, 0, stream>>>(Aop, wob, bo, (float*)d_out, 1.0f);
}